// Round 6
// baseline (1779.742 us; speedup 1.0000x reference)
//
#include <hip/hip_runtime.h>
#include <math.h>

#define VOCAB 50257
#define NCLS 20
#define BATCH 128
#define TLEN 2048

typedef float v2f __attribute__((ext_vector_type(2)));
typedef float v4f __attribute__((ext_vector_type(4)));

// Static device scratch (rewritten fully every call; graph-capture safe).
// P layout: [dir][v][lane][4] = {xr + bihr + bhhr, xz + bihz + bhhz, xn + bihn, pad}
__device__ float g_P[(size_t)2 * VOCAB * 256];   // 103 MB
__device__ float g_feats[BATCH * 256];

__device__ __forceinline__ float fsigmoid(float x) {
    return __builtin_amdgcn_rcpf(1.f + __expf(-x));
}
__device__ __forceinline__ float ftanh(float x) {
    float e = __expf(2.f * x);
    return 1.f - 2.f * __builtin_amdgcn_rcpf(e + 1.f);
}

// Forced packed fp32 FMA: d.lo += a.lo*b.lo, d.hi += a.hi*b.hi (compiler never forms this on its own)
#define PKFMA(A, H, W) asm("v_pk_fma_f32 %0, %1, %2, %0" : "+v"(A) : "v"(H), "v"(W));

// Load 64 floats (one gate's row for this lane) as 32 named v2f, PIN in VGPR pairs.
// Pairs (not quads) + narrow h live-window keep total pressure ~270 < 512 regs @ 1 wave/EU
// (R5 lesson: pinning quads + wide h window demanded 340 regs -> scratch spills).
#define LDW_PK(P, base) \
    v2f P##0,P##1,P##2,P##3,P##4,P##5,P##6,P##7,P##8,P##9,P##10,P##11,P##12,P##13,P##14,P##15, \
        P##16,P##17,P##18,P##19,P##20,P##21,P##22,P##23,P##24,P##25,P##26,P##27,P##28,P##29,P##30,P##31; \
    { const float4* w4_ = (const float4*)(base); float4 t_; \
      t_ = w4_[0];  P##0  = (v2f){t_.x,t_.y}; P##1  = (v2f){t_.z,t_.w}; \
      t_ = w4_[1];  P##2  = (v2f){t_.x,t_.y}; P##3  = (v2f){t_.z,t_.w}; \
      t_ = w4_[2];  P##4  = (v2f){t_.x,t_.y}; P##5  = (v2f){t_.z,t_.w}; \
      t_ = w4_[3];  P##6  = (v2f){t_.x,t_.y}; P##7  = (v2f){t_.z,t_.w}; \
      t_ = w4_[4];  P##8  = (v2f){t_.x,t_.y}; P##9  = (v2f){t_.z,t_.w}; \
      t_ = w4_[5];  P##10 = (v2f){t_.x,t_.y}; P##11 = (v2f){t_.z,t_.w}; \
      t_ = w4_[6];  P##12 = (v2f){t_.x,t_.y}; P##13 = (v2f){t_.z,t_.w}; \
      t_ = w4_[7];  P##14 = (v2f){t_.x,t_.y}; P##15 = (v2f){t_.z,t_.w}; \
      t_ = w4_[8];  P##16 = (v2f){t_.x,t_.y}; P##17 = (v2f){t_.z,t_.w}; \
      t_ = w4_[9];  P##18 = (v2f){t_.x,t_.y}; P##19 = (v2f){t_.z,t_.w}; \
      t_ = w4_[10]; P##20 = (v2f){t_.x,t_.y}; P##21 = (v2f){t_.z,t_.w}; \
      t_ = w4_[11]; P##22 = (v2f){t_.x,t_.y}; P##23 = (v2f){t_.z,t_.w}; \
      t_ = w4_[12]; P##24 = (v2f){t_.x,t_.y}; P##25 = (v2f){t_.z,t_.w}; \
      t_ = w4_[13]; P##26 = (v2f){t_.x,t_.y}; P##27 = (v2f){t_.z,t_.w}; \
      t_ = w4_[14]; P##28 = (v2f){t_.x,t_.y}; P##29 = (v2f){t_.z,t_.w}; \
      t_ = w4_[15]; P##30 = (v2f){t_.x,t_.y}; P##31 = (v2f){t_.z,t_.w}; } \
    asm("" : "+v"(P##0),  "+v"(P##1),  "+v"(P##2),  "+v"(P##3), \
             "+v"(P##4),  "+v"(P##5),  "+v"(P##6),  "+v"(P##7)); \
    asm("" : "+v"(P##8),  "+v"(P##9),  "+v"(P##10), "+v"(P##11), \
             "+v"(P##12), "+v"(P##13), "+v"(P##14), "+v"(P##15)); \
    asm("" : "+v"(P##16), "+v"(P##17), "+v"(P##18), "+v"(P##19), \
             "+v"(P##20), "+v"(P##21), "+v"(P##22), "+v"(P##23)); \
    asm("" : "+v"(P##24), "+v"(P##25), "+v"(P##26), "+v"(P##27), \
             "+v"(P##28), "+v"(P##29), "+v"(P##30), "+v"(P##31));

// One K-tile (4 h values = 2 v2f): 6 pk-FMAs into rotating chains; h live-window = 1 float4
#define KTILE(kk, WAr, WAz, WAn, WBr, WBz, WBn, cr, cz, cn, dr, dz, dn) \
    { float4 h4_ = hp[kk]; v2f hA_ = (v2f){h4_.x, h4_.y}, hB_ = (v2f){h4_.z, h4_.w}; \
      PKFMA(cr, hA_, WAr) PKFMA(cz, hA_, WAz) PKFMA(cn, hA_, WAn) \
      PKFMA(dr, hB_, WBr) PKFMA(dz, hB_, WBz) PKFMA(dn, hB_, WBn) }

// ---------------- Kernel A: P[dir][v][lane] = {emb[v]·wih_r + br', emb[v]·wih_z + bz', emb[v]·wih_n + bn_ih, 0}
__global__ __launch_bounds__(128)
__attribute__((amdgpu_waves_per_eu(1, 1)))
void precompute_P(
    const float* __restrict__ emb,
    const float* __restrict__ wih_f, const float* __restrict__ bih_f, const float* __restrict__ bhh_f,
    const float* __restrict__ wih_b, const float* __restrict__ bih_b, const float* __restrict__ bhh_b)
{
    const int lane = threadIdx.x & 63;
    const int dir  = threadIdx.x >> 6;          // wave-uniform
    const float* wih = dir ? wih_b : wih_f;
    const float* bih = dir ? bih_b : bih_f;
    const float* bhh = dir ? bhh_b : bhh_f;

    LDW_PK(wr, wih + (size_t)lane * 64)
    LDW_PK(wz, wih + (size_t)(64 + lane) * 64)
    LDW_PK(wn, wih + (size_t)(128 + lane) * 64)
    const float br = bih[lane] + bhh[lane];            // fold bhh_r / bhh_z here
    const float bz = bih[64 + lane] + bhh[64 + lane];
    const float bn = bih[128 + lane];                  // bhh_n stays separate (scaled by r)

    float4* Pd = (float4*)g_P + (size_t)dir * VOCAB * 64;

    for (int v = blockIdx.x; v < VOCAB; v += gridDim.x) {
        const float4* hp = (const float4*)(emb + (size_t)v * 64);  // wave-uniform -> scalar loads
        v2f qr0 = (v2f)(0.f), qr1 = (v2f)(0.f), qr2 = (v2f)(0.f), qr3 = (v2f)(0.f);
        v2f qz0 = (v2f)(0.f), qz1 = (v2f)(0.f), qz2 = (v2f)(0.f), qz3 = (v2f)(0.f);
        v2f qn0 = (v2f)(0.f), qn1 = (v2f)(0.f), qn2 = (v2f)(0.f), qn3 = (v2f)(0.f);
        KTILE(0,  wr0,  wz0,  wn0,  wr1,  wz1,  wn1,  qr0, qz0, qn0, qr1, qz1, qn1)
        KTILE(1,  wr2,  wz2,  wn2,  wr3,  wz3,  wn3,  qr2, qz2, qn2, qr3, qz3, qn3)
        KTILE(2,  wr4,  wz4,  wn4,  wr5,  wz5,  wn5,  qr0, qz0, qn0, qr1, qz1, qn1)
        KTILE(3,  wr6,  wz6,  wn6,  wr7,  wz7,  wn7,  qr2, qz2, qn2, qr3, qz3, qn3)
        KTILE(4,  wr8,  wz8,  wn8,  wr9,  wz9,  wn9,  qr0, qz0, qn0, qr1, qz1, qn1)
        KTILE(5,  wr10, wz10, wn10, wr11, wz11, wn11, qr2, qz2, qn2, qr3, qz3, qn3)
        KTILE(6,  wr12, wz12, wn12, wr13, wz13, wn13, qr0, qz0, qn0, qr1, qz1, qn1)
        KTILE(7,  wr14, wz14, wn14, wr15, wz15, wn15, qr2, qz2, qn2, qr3, qz3, qn3)
        KTILE(8,  wr16, wz16, wn16, wr17, wz17, wn17, qr0, qz0, qn0, qr1, qz1, qn1)
        KTILE(9,  wr18, wz18, wn18, wr19, wz19, wn19, qr2, qz2, qn2, qr3, qz3, qn3)
        KTILE(10, wr20, wz20, wn20, wr21, wz21, wn21, qr0, qz0, qn0, qr1, qz1, qn1)
        KTILE(11, wr22, wz22, wn22, wr23, wz23, wn23, qr2, qz2, qn2, qr3, qz3, qn3)
        KTILE(12, wr24, wz24, wn24, wr25, wz25, wn25, qr0, qz0, qn0, qr1, qz1, qn1)
        KTILE(13, wr26, wz26, wn26, wr27, wz27, wn27, qr2, qz2, qn2, qr3, qz3, qn3)
        KTILE(14, wr28, wz28, wn28, wr29, wz29, wn29, qr0, qz0, qn0, qr1, qz1, qn1)
        KTILE(15, wr30, wz30, wn30, wr31, wz31, wn31, qr2, qz2, qn2, qr3, qz3, qn3)
        v2f tr = (qr0 + qr1) + (qr2 + qr3);
        v2f tz = (qz0 + qz1) + (qz2 + qz3);
        v2f tn = (qn0 + qn1) + (qn2 + qn3);
        float4 o;
        o.x = tr.x + tr.y + br;
        o.y = tz.x + tz.y + bz;
        o.z = tn.x + tn.y + bn;
        o.w = 0.f;
        Pd[(size_t)v * 64 + lane] = o;                 // 64 lanes x 16B contiguous
    }
}

// ---------------- Kernel B: one wave per (dir,batch); no barriers; pinned pk weights; 4-deep prefetch
__global__ __launch_bounds__(64)
__attribute__((amdgpu_waves_per_eu(1, 1)))
void gru_seq(
    const int* __restrict__ tokens,
    const float* __restrict__ whh_f, const float* __restrict__ bhh_f,
    const float* __restrict__ whh_b, const float* __restrict__ bhh_b)
{
    const int lane = threadIdx.x;                 // hidden unit
    const int b = blockIdx.x >> 1;
    const int dir = blockIdx.x & 1;
    const float* whh = dir ? whh_b : whh_f;
    const float* bhh = dir ? bhh_b : bhh_f;
    const float4* P4 = (const float4*)g_P + (size_t)dir * VOCAB * 64;

    __shared__ __align__(16) float h_lds[64];
    __shared__ int tok_lds[TLEN];
    for (int t = lane; t < TLEN; t += 64) tok_lds[t] = tokens[b * TLEN + t];
    // single-wave block: lockstep; NO __syncthreads (would force vmcnt(0) drain per step).

    // 192 weight floats pinned as 96 VGPR pairs
    LDW_PK(wr, whh + (size_t)lane * 64)
    LDW_PK(wz, whh + (size_t)(64 + lane) * 64)
    LDW_PK(wn, whh + (size_t)(128 + lane) * 64)
    const float bn = bhh[128 + lane];

    h_lds[lane] = 0.f;
    float h = 0.f, sum = 0.f, mx = -INFINITY;

    auto rowAt = [&](int s) -> const float4* {
        int ss = s < TLEN ? s : TLEN - 1;               // clamp tail prefetches (values unused)
        int tok = tok_lds[dir ? (TLEN - 1 - ss) : ss];
        return P4 + (size_t)tok * 64;
    };

    float4 xg[4];
#pragma unroll
    for (int j = 0; j < 4; j++) xg[j] = rowAt(j)[lane];

    const float4* hp = (const float4*)h_lds;            // uniform-address reads = broadcast

    for (int s = 0; s < TLEN; s += 4) {
#pragma unroll
        for (int j = 0; j < 4; j++) {
            const float4 cur = xg[j];
            // prefetch step s+j+4: consumed 4 sub-steps later -> covers gather latency
            xg[j] = rowAt(s + j + 4)[lane];

            v2f qr0 = (v2f)(0.f), qr1 = (v2f)(0.f), qr2 = (v2f)(0.f), qr3 = (v2f)(0.f);
            v2f qz0 = (v2f)(0.f), qz1 = (v2f)(0.f), qz2 = (v2f)(0.f), qz3 = (v2f)(0.f);
            v2f qn0 = (v2f)(0.f), qn1 = (v2f)(0.f), qn2 = (v2f)(0.f), qn3 = (v2f)(0.f);
            KTILE(0,  wr0,  wz0,  wn0,  wr1,  wz1,  wn1,  qr0, qz0, qn0, qr1, qz1, qn1)
            KTILE(1,  wr2,  wz2,  wn2,  wr3,  wz3,  wn3,  qr2, qz2, qn2, qr3, qz3, qn3)
            KTILE(2,  wr4,  wz4,  wn4,  wr5,  wz5,  wn5,  qr0, qz0, qn0, qr1, qz1, qn1)
            KTILE(3,  wr6,  wz6,  wn6,  wr7,  wz7,  wn7,  qr2, qz2, qn2, qr3, qz3, qn3)
            KTILE(4,  wr8,  wz8,  wn8,  wr9,  wz9,  wn9,  qr0, qz0, qn0, qr1, qz1, qn1)
            KTILE(5,  wr10, wz10, wn10, wr11, wz11, wn11, qr2, qz2, qn2, qr3, qz3, qn3)
            KTILE(6,  wr12, wz12, wn12, wr13, wz13, wn13, qr0, qz0, qn0, qr1, qz1, qn1)
            KTILE(7,  wr14, wz14, wn14, wr15, wz15, wn15, qr2, qz2, qn2, qr3, qz3, qn3)
            KTILE(8,  wr16, wz16, wn16, wr17, wz17, wn17, qr0, qz0, qn0, qr1, qz1, qn1)
            KTILE(9,  wr18, wz18, wn18, wr19, wz19, wn19, qr2, qz2, qn2, qr3, qz3, qn3)
            KTILE(10, wr20, wz20, wn20, wr21, wz21, wn21, qr0, qz0, qn0, qr1, qz1, qn1)
            KTILE(11, wr22, wz22, wn22, wr23, wz23, wn23, qr2, qz2, qn2, qr3, qz3, qn3)
            KTILE(12, wr24, wz24, wn24, wr25, wz25, wn25, qr0, qz0, qn0, qr1, qz1, qn1)
            KTILE(13, wr26, wz26, wn26, wr27, wz27, wn27, qr2, qz2, qn2, qr3, qz3, qn3)
            KTILE(14, wr28, wz28, wn28, wr29, wz29, wn29, qr0, qz0, qn0, qr1, qz1, qn1)
            KTILE(15, wr30, wz30, wn30, wr31, wz31, wn31, qr2, qz2, qn2, qr3, qz3, qn3)
            v2f tr = (qr0 + qr1) + (qr2 + qr3);
            v2f tz = (qz0 + qz1) + (qz2 + qz3);
            v2f tn = (qn0 + qn1) + (qn2 + qn3);
            const float hr = tr.x + tr.y;
            const float hz = tz.x + tz.y;
            const float hn = tn.x + tn.y;

            const float r = fsigmoid(cur.x + hr);       // biases pre-folded into P
            const float z = fsigmoid(cur.y + hz);
            const float n = ftanh(cur.z + r * (hn + bn));
            h = fmaf(z, h - n, n);                      // (1-z)*n + z*h
            sum += h;
            mx = fmaxf(mx, h);

            __builtin_amdgcn_wave_barrier();            // scheduling fence only (no s_barrier)
            h_lds[lane] = h;
            __builtin_amdgcn_wave_barrier();
        }
    }

    g_feats[b * 256 + dir * 64 + lane] = sum * (1.f / TLEN);
    g_feats[b * 256 + 128 + dir * 64 + lane] = mx;
}

// ---------------- Kernel C: classifier  out = W2 @ gelu(W1 @ feats + b1) + b2
__global__ __launch_bounds__(64) void classifier(
    const float* __restrict__ w1, const float* __restrict__ b1,
    const float* __restrict__ w2, const float* __restrict__ b2,
    float* __restrict__ out)
{
    const int b = blockIdx.x;
    const int i = threadIdx.x;
    __shared__ float f[256];
    __shared__ float hid[64];
    for (int c = i; c < 256; c += 64) f[c] = g_feats[b * 256 + c];
    __syncthreads();

    float acc = b1[i];
    const float* wrow = w1 + (size_t)i * 256;
#pragma unroll 16
    for (int c = 0; c < 256; c++) acc = fmaf(f[c], wrow[c], acc);
    hid[i] = acc * 0.5f * (1.f + erff(acc * 0.70710678118654752f));   // exact GELU
    __syncthreads();

    if (i < NCLS) {
        float o = b2[i];
        const float* w2r = w2 + (size_t)i * 64;
#pragma unroll
        for (int j = 0; j < 64; j++) o = fmaf(hid[j], w2r[j], o);
        out[b * NCLS + i] = o;
    }
}

extern "C" void kernel_launch(void* const* d_in, const int* in_sizes, int n_in,
                              void* d_out, int out_size, void* d_ws, size_t ws_size,
                              hipStream_t stream) {
    const int*   tokens = (const int*)  d_in[0];
    const float* emb    = (const float*)d_in[1];
    const float* wih_f  = (const float*)d_in[2];
    const float* whh_f  = (const float*)d_in[3];
    const float* bih_f  = (const float*)d_in[4];
    const float* bhh_f  = (const float*)d_in[5];
    const float* wih_b  = (const float*)d_in[6];
    const float* whh_b  = (const float*)d_in[7];
    const float* bih_b  = (const float*)d_in[8];
    const float* bhh_b  = (const float*)d_in[9];
    const float* w1     = (const float*)d_in[10];
    const float* b1     = (const float*)d_in[11];
    const float* w2     = (const float*)d_in[12];
    const float* b2     = (const float*)d_in[13];
    float* out = (float*)d_out;

    precompute_P<<<1024, 128, 0, stream>>>(emb, wih_f, bih_f, bhh_f, wih_b, bih_b, bhh_b);
    gru_seq<<<2 * BATCH, 64, 0, stream>>>(tokens, whh_f, bhh_f, whh_b, bhh_b);
    classifier<<<BATCH, 64, 0, stream>>>(w1, b1, w2, b2, out);
}